// Round 2
// baseline (2485.189 us; speedup 1.0000x reference)
//
#include <hip/hip_runtime.h>

typedef short short8 __attribute__((ext_vector_type(8)));
typedef float f32x4 __attribute__((ext_vector_type(4)));

#define ROWS 65536     // B*C*S = 1024*64
#define NSEQ 1024      // B*C
#define NELT 16777216  // B*S*C*D per tensor

__device__ __forceinline__ float b2f(unsigned short u) {
    return __uint_as_float(((unsigned)u) << 16);
}
__device__ __forceinline__ unsigned short f2b(float f) {
    unsigned u = __float_as_uint(f);
    u += 0x7FFF + ((u >> 16) & 1);   // RTN-even
    return (unsigned short)(u >> 16);
}
// Markidis split: f ~= b2f(hi) + b2f(lo), residual ~2^-18 relative
__device__ __forceinline__ void split2(float f, unsigned short& hi, unsigned short& lo) {
    unsigned short h = f2b(f);
    hi = h;
    lo = f2b(f - b2f(h));
}
// row r of the (BC*S, D) flattened view -> flat offset into x (B,S,C,D)
__device__ __forceinline__ int xrow_off(int r) {
    int n = r >> 6, s = r & 63;      // n = b*128+c, s = token
    int b = n >> 7, c = n & 127;
    return (((b << 6) + s) * 128 + c) << 8;  // ((b*64+s)*128+c)*256
}
// XOR-swizzled LDS element offset for a 64x128 bf16 tile (8-elem chunks).
// Keeps 16B alignment for short8 reads; 8 consecutive rows cover all banks.
__device__ __forceinline__ int sw128(int row, int k) {
    return row * 128 + ((((k >> 3) ^ (row & 7)) << 3) | (k & 7));
}

// ---------------- LayerNorm stats: mean + rstd per row ----------------
__global__ __launch_bounds__(256) void ln_stats(const float* __restrict__ xs,
                                                const float* __restrict__ xt,
                                                float2* __restrict__ st_s,
                                                float2* __restrict__ st_t) {
    int wv = threadIdx.x >> 6, l = threadIdx.x & 63;
    int gid = blockIdx.x * 4 + wv;                    // 0..131071
    const float* X = (gid < ROWS) ? xs : xt;
    float2* ST = (gid < ROWS) ? st_s : st_t;
    int r = gid & (ROWS - 1);
    float4 v = *(const float4*)(X + xrow_off(r) + l * 4);
    float s1 = v.x + v.y + v.z + v.w;
    float s2 = v.x * v.x + v.y * v.y + v.z * v.z + v.w * v.w;
    #pragma unroll
    for (int o = 32; o > 0; o >>= 1) {
        s1 += __shfl_down(s1, o);
        s2 += __shfl_down(s2, o);
    }
    if (l == 0) {
        float mu = s1 * (1.f / 256.f);
        float var = s2 * (1.f / 256.f) - mu * mu;
        ST[r] = make_float2(mu, rsqrtf(var + 1e-5f));
    }
}

// ---------------- fused LN + QKV projection GEMM (bf16x3) ----------------
// grid (1024, 8): y<4 -> Q cols, y in 4..5 -> K, y in 6..7 -> V
__global__ __launch_bounds__(256) void qkv_gemm(
    const float* __restrict__ xq, const float2* __restrict__ stq,
    const float* __restrict__ gq, const float* __restrict__ btq,
    const float* __restrict__ xkv, const float2* __restrict__ stkv,
    const float* __restrict__ gkv, const float* __restrict__ btkv,
    const float* __restrict__ Wq, const float* __restrict__ Wk, const float* __restrict__ Wv,
    const float* __restrict__ bq, const float* __restrict__ bk, const float* __restrict__ bv,
    unsigned short* __restrict__ Qb, unsigned short* __restrict__ Kb,
    unsigned short* __restrict__ Vb)
{
    __shared__ unsigned short Ah[64 * 128], Al[64 * 128];
    __shared__ unsigned short Bh[64 * 128], Bl[64 * 128];
    const int mt = blockIdx.x, nt = blockIdx.y, t = threadIdx.x;
    const float* X; const float2* ST; const float* G; const float* BT;
    const float* W; const float* bias; unsigned short* Out;
    int ldw, wcol0, ldo;
    if (nt < 4)      { X = xq;  ST = stq;  G = gq;  BT = btq;  W = Wq; ldw = 256; wcol0 = nt * 64;       bias = bq; Out = Qb; ldo = 256; }
    else if (nt < 6) { X = xkv; ST = stkv; G = gkv; BT = btkv; W = Wk; ldw = 128; wcol0 = (nt - 4) * 64; bias = bk; Out = Kb; ldo = 128; }
    else             { X = xkv; ST = stkv; G = gkv; BT = btkv; W = Wv; ldw = 128; wcol0 = (nt - 6) * 64; bias = bv; Out = Vb; ldo = 128; }
    const int r0 = mt * 64;
    const int lm = t & 15, lq = (t & 63) >> 4, m16 = (t >> 6) * 16;
    f32x4 acc[4] = {{0,0,0,0},{0,0,0,0},{0,0,0,0},{0,0,0,0}};
    #pragma unroll 1
    for (int kh = 0; kh < 2; ++kh) {
        if (kh) __syncthreads();
        // A tile: 64 rows x 128 cols (K-half), LN-applied, hi/lo bf16, swizzled
        #pragma unroll
        for (int it = 0; it < 8; ++it) {
            int idx = it * 256 + t;              // 0..2047 float4 slots
            int row = idx >> 5, seg = idx & 31;
            int col = kh * 128 + seg * 4;
            int r = r0 + row;
            const float4 xv = *(const float4*)(X + xrow_off(r) + col);
            float2 stv = ST[r];
            const float4 gv = *(const float4*)(G + col);
            const float4 b4 = *(const float4*)(BT + col);
            float v0 = (xv.x - stv.x) * stv.y * gv.x + b4.x;
            float v1 = (xv.y - stv.x) * stv.y * gv.y + b4.y;
            float v2 = (xv.z - stv.x) * stv.y * gv.z + b4.z;
            float v3 = (xv.w - stv.x) * stv.y * gv.w + b4.w;
            ushort4 oh, ol;
            split2(v0, oh.x, ol.x); split2(v1, oh.y, ol.y);
            split2(v2, oh.z, ol.z); split2(v3, oh.w, ol.w);
            *(ushort4*)&Ah[sw128(row, seg * 4)] = oh;
            *(ushort4*)&Al[sw128(row, seg * 4)] = ol;
        }
        // B tile: W[kh*128+k][wcol0+n] -> Bs[n][k] hi/lo, swizzled
        #pragma unroll
        for (int it = 0; it < 8; ++it) {
            int idx = it * 256 + t;
            int k = idx >> 4, sg = idx & 15;
            const float4 w4 = *(const float4*)(W + (kh * 128 + k) * ldw + wcol0 + sg * 4);
            unsigned short h, l;
            split2(w4.x, h, l); Bh[sw128(sg * 4 + 0, k)] = h; Bl[sw128(sg * 4 + 0, k)] = l;
            split2(w4.y, h, l); Bh[sw128(sg * 4 + 1, k)] = h; Bl[sw128(sg * 4 + 1, k)] = l;
            split2(w4.z, h, l); Bh[sw128(sg * 4 + 2, k)] = h; Bl[sw128(sg * 4 + 2, k)] = l;
            split2(w4.w, h, l); Bh[sw128(sg * 4 + 3, k)] = h; Bl[sw128(sg * 4 + 3, k)] = l;
        }
        __syncthreads();
        #pragma unroll
        for (int kk = 0; kk < 4; ++kk) {
            int k0 = kk * 32 + lq * 8;
            short8 ah = *(const short8*)&Ah[sw128(m16 + lm, k0)];
            short8 al = *(const short8*)&Al[sw128(m16 + lm, k0)];
            #pragma unroll
            for (int ct = 0; ct < 4; ++ct) {
                short8 bh = *(const short8*)&Bh[sw128(ct * 16 + lm, k0)];
                short8 bl = *(const short8*)&Bl[sw128(ct * 16 + lm, k0)];
                acc[ct] = __builtin_amdgcn_mfma_f32_16x16x32_bf16(ah, bh, acc[ct], 0, 0, 0);
                acc[ct] = __builtin_amdgcn_mfma_f32_16x16x32_bf16(al, bh, acc[ct], 0, 0, 0);
                acc[ct] = __builtin_amdgcn_mfma_f32_16x16x32_bf16(ah, bl, acc[ct], 0, 0, 0);
            }
        }
    }
    #pragma unroll
    for (int ct = 0; ct < 4; ++ct) {
        #pragma unroll
        for (int rg = 0; rg < 4; ++rg) {
            int row = m16 + lq * 4 + rg;
            int coll = wcol0 + ct * 16 + lm;
            float v = acc[ct][rg] + bias[coll];
            Out[(r0 + row) * ldo + coll] = f2b(v);
        }
    }
}

// ---------------- attention: one block per sequence ----------------
__global__ __launch_bounds__(256) void attn_kernel(
    const unsigned short* __restrict__ Qb, const unsigned short* __restrict__ Kb,
    const unsigned short* __restrict__ Vb, float* __restrict__ Ob)
{
    __shared__ unsigned short ks[64 * 128];
    __shared__ unsigned short vs[64 * 128];
    const int n = blockIdx.x, t = threadIdx.x;
    const int r0 = n * 64;
    #pragma unroll
    for (int it = 0; it < 8; ++it) {
        int idx = it * 256 + t;
        int row = idx >> 5, seg = idx & 31;
        *(ushort4*)&ks[row * 128 + seg * 4] = *(const ushort4*)&Kb[(r0 + row) * 128 + seg * 4];
        *(ushort4*)&vs[row * 128 + seg * 4] = *(const ushort4*)&Vb[(r0 + row) * 128 + seg * 4];
    }
    __syncthreads();
    const float scale = 0.17677669529663687f;  // 1/sqrt(32)
    #pragma unroll 1
    for (int rep = 0; rep < 2; ++rep) {
        int item = rep * 256 + t;
        int h = item >> 6, s = item & 63, g = h >> 1;  // wave = one head
        float q_r[32];
        #pragma unroll
        for (int d4 = 0; d4 < 8; ++d4) {
            ushort4 q4 = *(const ushort4*)&Qb[(r0 + s) * 256 + h * 32 + d4 * 4];
            q_r[d4 * 4 + 0] = b2f(q4.x); q_r[d4 * 4 + 1] = b2f(q4.y);
            q_r[d4 * 4 + 2] = b2f(q4.z); q_r[d4 * 4 + 3] = b2f(q4.w);
        }
        float sc[64], mx = -3.0e38f;
        #pragma unroll
        for (int j = 0; j < 64; ++j) {
            float dot = 0.f;
            #pragma unroll
            for (int d4 = 0; d4 < 8; ++d4) {
                ushort4 k4 = *(const ushort4*)&ks[j * 128 + g * 32 + d4 * 4];
                dot += q_r[d4 * 4 + 0] * b2f(k4.x) + q_r[d4 * 4 + 1] * b2f(k4.y)
                     + q_r[d4 * 4 + 2] * b2f(k4.z) + q_r[d4 * 4 + 3] * b2f(k4.w);
            }
            sc[j] = dot;
            mx = fmaxf(mx, dot);
        }
        float sum = 0.f, acc[32];
        #pragma unroll
        for (int d = 0; d < 32; ++d) acc[d] = 0.f;
        #pragma unroll
        for (int j = 0; j < 64; ++j) {
            float p = __expf((sc[j] - mx) * scale);
            sum += p;
            #pragma unroll
            for (int d4 = 0; d4 < 8; ++d4) {
                ushort4 v4 = *(const ushort4*)&vs[j * 128 + g * 32 + d4 * 4];
                acc[d4 * 4 + 0] += p * b2f(v4.x); acc[d4 * 4 + 1] += p * b2f(v4.y);
                acc[d4 * 4 + 2] += p * b2f(v4.z); acc[d4 * 4 + 3] += p * b2f(v4.w);
            }
        }
        float inv = 1.f / sum;
        #pragma unroll
        for (int d4 = 0; d4 < 8; ++d4) {
            float4 o;
            o.x = acc[d4 * 4 + 0] * inv; o.y = acc[d4 * 4 + 1] * inv;
            o.z = acc[d4 * 4 + 2] * inv; o.w = acc[d4 * 4 + 3] * inv;
            *(float4*)&Ob[(r0 + s) * 256 + h * 32 + d4 * 4] = o;
        }
    }
}

// ------- O-projection GEMM (bf16x3) + gate + residual + transpose -------
__global__ __launch_bounds__(256) void oproj_gemm(
    const float* __restrict__ Ain, const float* __restrict__ Wo,
    const float* __restrict__ bo, const float* __restrict__ Xres,
    const float* __restrict__ gate, float* __restrict__ Out)
{
    __shared__ unsigned short Ah[64 * 128], Al[64 * 128];
    __shared__ unsigned short Bh[64 * 128], Bl[64 * 128];
    const int mt = blockIdx.x, nt = blockIdx.y, t = threadIdx.x;
    const int r0 = mt * 64, n0 = nt * 64;
    const int lm = t & 15, lq = (t & 63) >> 4, m16 = (t >> 6) * 16;
    f32x4 acc[4] = {{0,0,0,0},{0,0,0,0},{0,0,0,0},{0,0,0,0}};
    #pragma unroll 1
    for (int kh = 0; kh < 2; ++kh) {
        if (kh) __syncthreads();
        #pragma unroll
        for (int it = 0; it < 8; ++it) {
            int idx = it * 256 + t;
            int row = idx >> 5, seg = idx & 31;
            const float4 a4 = *(const float4*)(Ain + (r0 + row) * 256 + kh * 128 + seg * 4);
            ushort4 oh, ol;
            split2(a4.x, oh.x, ol.x); split2(a4.y, oh.y, ol.y);
            split2(a4.z, oh.z, ol.z); split2(a4.w, oh.w, ol.w);
            *(ushort4*)&Ah[sw128(row, seg * 4)] = oh;
            *(ushort4*)&Al[sw128(row, seg * 4)] = ol;
        }
        #pragma unroll
        for (int it = 0; it < 8; ++it) {
            int idx = it * 256 + t;
            int k = idx >> 4, sg = idx & 15;
            const float4 w4 = *(const float4*)(Wo + (kh * 128 + k) * 256 + n0 + sg * 4);
            unsigned short h, l;
            split2(w4.x, h, l); Bh[sw128(sg * 4 + 0, k)] = h; Bl[sw128(sg * 4 + 0, k)] = l;
            split2(w4.y, h, l); Bh[sw128(sg * 4 + 1, k)] = h; Bl[sw128(sg * 4 + 1, k)] = l;
            split2(w4.z, h, l); Bh[sw128(sg * 4 + 2, k)] = h; Bl[sw128(sg * 4 + 2, k)] = l;
            split2(w4.w, h, l); Bh[sw128(sg * 4 + 3, k)] = h; Bl[sw128(sg * 4 + 3, k)] = l;
        }
        __syncthreads();
        #pragma unroll
        for (int kk = 0; kk < 4; ++kk) {
            int k0 = kk * 32 + lq * 8;
            short8 ah = *(const short8*)&Ah[sw128(m16 + lm, k0)];
            short8 al = *(const short8*)&Al[sw128(m16 + lm, k0)];
            #pragma unroll
            for (int ct = 0; ct < 4; ++ct) {
                short8 bh = *(const short8*)&Bh[sw128(ct * 16 + lm, k0)];
                short8 bl = *(const short8*)&Bl[sw128(ct * 16 + lm, k0)];
                acc[ct] = __builtin_amdgcn_mfma_f32_16x16x32_bf16(ah, bh, acc[ct], 0, 0, 0);
                acc[ct] = __builtin_amdgcn_mfma_f32_16x16x32_bf16(al, bh, acc[ct], 0, 0, 0);
                acc[ct] = __builtin_amdgcn_mfma_f32_16x16x32_bf16(ah, bl, acc[ct], 0, 0, 0);
            }
        }
    }
    float sig = 1.f / (1.f + __expf(-gate[0]));
    #pragma unroll
    for (int ct = 0; ct < 4; ++ct) {
        #pragma unroll
        for (int rg = 0; rg < 4; ++rg) {
            int row = m16 + lq * 4 + rg;
            int col = n0 + ct * 16 + lm;
            int oidx = xrow_off(r0 + row) + col;
            Out[oidx] = Xres[oidx] + sig * (acc[ct][rg] + bo[col]);
        }
    }
}

extern "C" void kernel_launch(void* const* d_in, const int* in_sizes, int n_in,
                              void* d_out, int out_size, void* d_ws, size_t ws_size,
                              hipStream_t stream) {
    const float* x_spec = (const float*)d_in[0];
    const float* x_spat = (const float*)d_in[1];
    const float* ln_g[4] = {(const float*)d_in[2], (const float*)d_in[4],
                            (const float*)d_in[6], (const float*)d_in[8]};
    const float* ln_b[4] = {(const float*)d_in[3], (const float*)d_in[5],
                            (const float*)d_in[7], (const float*)d_in[9]};
    char* ws = (char*)d_ws;
    // workspace layout (~129 MiB total)
    float2* st_spec = (float2*)ws;                              // 512 KiB
    float2* st_spat = (float2*)(ws + ROWS * 8);                 // 512 KiB
    unsigned short* Qb = (unsigned short*)(ws + 2 * ROWS * 8);  // 32 MiB bf16
    unsigned short* Kb = Qb + (size_t)ROWS * 256;               // 16 MiB bf16
    unsigned short* Vb = Kb + (size_t)ROWS * 128;               // 16 MiB bf16
    float* Ab = (float*)(Vb + (size_t)ROWS * 128);              // 64 MiB fp32

    ln_stats<<<32768, 256, 0, stream>>>(x_spec, x_spat, st_spec, st_spat);

    for (int dir = 0; dir < 2; ++dir) {
        int base = 10 + dir * 8;
        const float* Wq = (const float*)d_in[base + 0];
        const float* bq = (const float*)d_in[base + 1];
        const float* Wk = (const float*)d_in[base + 2];
        const float* bk = (const float*)d_in[base + 3];
        const float* Wv = (const float*)d_in[base + 4];
        const float* bv = (const float*)d_in[base + 5];
        const float* Wo = (const float*)d_in[base + 6];
        const float* bo = (const float*)d_in[base + 7];
        const float* gate = (const float*)d_in[26 + dir];
        const float* xq   = dir == 0 ? x_spec : x_spat;
        const float* xkv  = dir == 0 ? x_spat : x_spec;
        const float2* stq  = dir == 0 ? st_spec : st_spat;
        const float2* stkv = dir == 0 ? st_spat : st_spec;
        const float* gq   = dir == 0 ? ln_g[0] : ln_g[2];
        const float* btq  = dir == 0 ? ln_b[0] : ln_b[2];
        const float* gkv  = dir == 0 ? ln_g[3] : ln_g[1];
        const float* btkv = dir == 0 ? ln_b[3] : ln_b[1];
        float* outp = (float*)d_out + (size_t)dir * NELT;

        qkv_gemm<<<dim3(1024, 8), 256, 0, stream>>>(
            xq, stq, gq, btq, xkv, stkv, gkv, btkv,
            Wq, Wk, Wv, bq, bk, bv, Qb, Kb, Vb);
        attn_kernel<<<1024, 256, 0, stream>>>(Qb, Kb, Vb, Ab);
        oproj_gemm<<<dim3(1024, 4), 256, 0, stream>>>(Ab, Wo, bo, xq, gate, outp);
    }
}

// Round 3
// 984.535 us; speedup vs baseline: 2.5242x; 2.5242x over previous
//
#include <hip/hip_runtime.h>

typedef short short8 __attribute__((ext_vector_type(8)));
typedef float f32x4 __attribute__((ext_vector_type(4)));

#define ROWS 65536     // B*C*S = 1024*64
#define NSEQ 1024      // B*C
#define NELT 16777216  // B*S*C*D per tensor

__device__ __forceinline__ float b2f(unsigned short u) {
    return __uint_as_float(((unsigned)u) << 16);
}
__device__ __forceinline__ unsigned short f2b(float f) {
    unsigned u = __float_as_uint(f);
    u += 0x7FFF + ((u >> 16) & 1);   // RTN-even
    return (unsigned short)(u >> 16);
}
// Markidis split: f ~= b2f(hi) + b2f(lo), residual ~2^-18 relative
__device__ __forceinline__ void split2(float f, unsigned short& hi, unsigned short& lo) {
    unsigned short h = f2b(f);
    hi = h;
    lo = f2b(f - b2f(h));
}
// row r of the (BC*S, D) flattened view -> flat offset into x (B,S,C,D)
__device__ __forceinline__ int xrow_off(int r) {
    int n = r >> 6, s = r & 63;      // n = b*128+c, s = token
    int b = n >> 7, c = n & 127;
    return (((b << 6) + s) * 128 + c) << 8;  // ((b*64+s)*128+c)*256
}
// XOR-swizzled LDS element offset for a 64x128 bf16 tile (8-elem chunks).
__device__ __forceinline__ int sw128(int row, int k) {
    return row * 128 + ((((k >> 3) ^ (row & 7)) << 3) | (k & 7));
}

// ---------------- LayerNorm stats: mean + rstd per row ----------------
__global__ __launch_bounds__(256) void ln_stats(const float* __restrict__ xs,
                                                const float* __restrict__ xt,
                                                float2* __restrict__ st_s,
                                                float2* __restrict__ st_t) {
    int wv = threadIdx.x >> 6, l = threadIdx.x & 63;
    int gid = blockIdx.x * 4 + wv;                    // 0..131071
    const float* X = (gid < ROWS) ? xs : xt;
    float2* ST = (gid < ROWS) ? st_s : st_t;
    int r = gid & (ROWS - 1);
    float4 v = *(const float4*)(X + xrow_off(r) + l * 4);
    float s1 = v.x + v.y + v.z + v.w;
    float s2 = v.x * v.x + v.y * v.y + v.z * v.z + v.w * v.w;
    #pragma unroll
    for (int o = 32; o > 0; o >>= 1) {
        s1 += __shfl_down(s1, o);
        s2 += __shfl_down(s2, o);
    }
    if (l == 0) {
        float mu = s1 * (1.f / 256.f);
        float var = s2 * (1.f / 256.f) - mu * mu;
        ST[r] = make_float2(mu, rsqrtf(var + 1e-5f));
    }
}

// ---------------- fused LN + QKV projection GEMM (bf16x3) ----------------
// grid (1024, 8): y<4 -> Q cols, y in 4..5 -> K, y in 6..7 -> V
__global__ __launch_bounds__(256) void qkv_gemm(
    const float* __restrict__ xq, const float2* __restrict__ stq,
    const float* __restrict__ gq, const float* __restrict__ btq,
    const float* __restrict__ xkv, const float2* __restrict__ stkv,
    const float* __restrict__ gkv, const float* __restrict__ btkv,
    const float* __restrict__ Wq, const float* __restrict__ Wk, const float* __restrict__ Wv,
    const float* __restrict__ bq, const float* __restrict__ bk, const float* __restrict__ bv,
    unsigned short* __restrict__ Qb, unsigned short* __restrict__ Kb,
    unsigned short* __restrict__ Vb)
{
    __shared__ unsigned short Ah[64 * 128], Al[64 * 128];
    __shared__ unsigned short Bh[64 * 128], Bl[64 * 128];
    const int mt = blockIdx.x, nt = blockIdx.y, t = threadIdx.x;
    const float* X; const float2* ST; const float* G; const float* BT;
    const float* W; const float* bias; unsigned short* Out;
    int ldw, wcol0, ldo;
    if (nt < 4)      { X = xq;  ST = stq;  G = gq;  BT = btq;  W = Wq; ldw = 256; wcol0 = nt * 64;       bias = bq; Out = Qb; ldo = 256; }
    else if (nt < 6) { X = xkv; ST = stkv; G = gkv; BT = btkv; W = Wk; ldw = 128; wcol0 = (nt - 4) * 64; bias = bk; Out = Kb; ldo = 128; }
    else             { X = xkv; ST = stkv; G = gkv; BT = btkv; W = Wv; ldw = 128; wcol0 = (nt - 6) * 64; bias = bv; Out = Vb; ldo = 128; }
    const int r0 = mt * 64;
    const int lm = t & 15, lq = (t & 63) >> 4, m16 = (t >> 6) * 16;
    f32x4 acc[4] = {{0,0,0,0},{0,0,0,0},{0,0,0,0},{0,0,0,0}};
    #pragma unroll 1
    for (int kh = 0; kh < 2; ++kh) {
        if (kh) __syncthreads();
        #pragma unroll
        for (int it = 0; it < 8; ++it) {
            int idx = it * 256 + t;              // 0..2047 float4 slots
            int row = idx >> 5, seg = idx & 31;
            int col = kh * 128 + seg * 4;
            int r = r0 + row;
            const float4 xv = *(const float4*)(X + xrow_off(r) + col);
            float2 stv = ST[r];
            const float4 gv = *(const float4*)(G + col);
            const float4 b4 = *(const float4*)(BT + col);
            float v0 = (xv.x - stv.x) * stv.y * gv.x + b4.x;
            float v1 = (xv.y - stv.x) * stv.y * gv.y + b4.y;
            float v2 = (xv.z - stv.x) * stv.y * gv.z + b4.z;
            float v3 = (xv.w - stv.x) * stv.y * gv.w + b4.w;
            ushort4 oh, ol;
            split2(v0, oh.x, ol.x); split2(v1, oh.y, ol.y);
            split2(v2, oh.z, ol.z); split2(v3, oh.w, ol.w);
            *(ushort4*)&Ah[sw128(row, seg * 4)] = oh;
            *(ushort4*)&Al[sw128(row, seg * 4)] = ol;
        }
        #pragma unroll
        for (int it = 0; it < 8; ++it) {
            int idx = it * 256 + t;
            int k = idx >> 4, sg = idx & 15;
            const float4 w4 = *(const float4*)(W + (kh * 128 + k) * ldw + wcol0 + sg * 4);
            unsigned short h, l;
            split2(w4.x, h, l); Bh[sw128(sg * 4 + 0, k)] = h; Bl[sw128(sg * 4 + 0, k)] = l;
            split2(w4.y, h, l); Bh[sw128(sg * 4 + 1, k)] = h; Bl[sw128(sg * 4 + 1, k)] = l;
            split2(w4.z, h, l); Bh[sw128(sg * 4 + 2, k)] = h; Bl[sw128(sg * 4 + 2, k)] = l;
            split2(w4.w, h, l); Bh[sw128(sg * 4 + 3, k)] = h; Bl[sw128(sg * 4 + 3, k)] = l;
        }
        __syncthreads();
        #pragma unroll
        for (int kk = 0; kk < 4; ++kk) {
            int k0 = kk * 32 + lq * 8;
            short8 ah = *(const short8*)&Ah[sw128(m16 + lm, k0)];
            short8 al = *(const short8*)&Al[sw128(m16 + lm, k0)];
            #pragma unroll
            for (int ct = 0; ct < 4; ++ct) {
                short8 bh = *(const short8*)&Bh[sw128(ct * 16 + lm, k0)];
                short8 bl = *(const short8*)&Bl[sw128(ct * 16 + lm, k0)];
                acc[ct] = __builtin_amdgcn_mfma_f32_16x16x32_bf16(ah, bh, acc[ct], 0, 0, 0);
                acc[ct] = __builtin_amdgcn_mfma_f32_16x16x32_bf16(al, bh, acc[ct], 0, 0, 0);
                acc[ct] = __builtin_amdgcn_mfma_f32_16x16x32_bf16(ah, bl, acc[ct], 0, 0, 0);
            }
        }
    }
    #pragma unroll
    for (int ct = 0; ct < 4; ++ct) {
        #pragma unroll
        for (int rg = 0; rg < 4; ++rg) {
            int row = m16 + lq * 4 + rg;
            int coll = wcol0 + ct * 16 + lm;
            float v = acc[ct][rg] + bias[coll];
            Out[(r0 + row) * ldo + coll] = f2b(v);
        }
    }
}

// ---------------- MFMA attention: one block per sequence ----------------
// 4 waves; wave g owns heads 2g, 2g+1 (both use KV head g).
// QK^T: M64 N64 K32 per head (16 mfma); softmax in C-layout registers with
// 16-lane shfl_xor reductions; P -> LDS (A-layout transform); PV: M64 N32 K64.
__global__ __launch_bounds__(256) void attn_kernel(
    const unsigned short* __restrict__ Qb, const unsigned short* __restrict__ Kb,
    const unsigned short* __restrict__ Vb, float* __restrict__ Ob)
{
    __shared__ unsigned short VT[128 * 72];      // V^T: [dim][key], stride 72
    __shared__ unsigned short Pl[4 * 64 * 72];   // per-wave P, stride 72
    const int n = blockIdx.x, t = threadIdx.x;
    const int r0 = n * 64;
    // stage V transposed
    #pragma unroll
    for (int it = 0; it < 8; ++it) {
        int idx = it * 256 + t;
        int row = idx >> 5, seg = idx & 31;
        ushort4 v4 = *(const ushort4*)&Vb[(r0 + row) * 128 + seg * 4];
        VT[(seg * 4 + 0) * 72 + row] = v4.x;
        VT[(seg * 4 + 1) * 72 + row] = v4.y;
        VT[(seg * 4 + 2) * 72 + row] = v4.z;
        VT[(seg * 4 + 3) * 72 + row] = v4.w;
    }
    __syncthreads();
    const int wave = t >> 6, l = t & 63, lm = l & 15, lq = l >> 4;
    const int g = wave;
    unsigned short* Pw = &Pl[wave * 64 * 72];
    const float scale = 0.17677669529663687f;    // 1/sqrt(32)
    short8 kf[4];
    #pragma unroll
    for (int nt = 0; nt < 4; ++nt)
        kf[nt] = *(const short8*)&Kb[(r0 + nt * 16 + lm) * 128 + g * 32 + lq * 8];
    #pragma unroll 1
    for (int hi = 0; hi < 2; ++hi) {
        const int h = g * 2 + hi;
        // scores S[row][key], C-layout: row = mt*16 + lq*4 + rg, col = nt*16 + lm
        f32x4 s[4][4];
        #pragma unroll
        for (int mt = 0; mt < 4; ++mt) {
            short8 qf = *(const short8*)&Qb[(r0 + mt * 16 + lm) * 256 + h * 32 + lq * 8];
            #pragma unroll
            for (int nt = 0; nt < 4; ++nt) {
                f32x4 z = {0, 0, 0, 0};
                s[mt][nt] = __builtin_amdgcn_mfma_f32_16x16x32_bf16(qf, kf[nt], z, 0, 0, 0);
            }
        }
        // softmax per row + write normalized P (bf16) to wave-private LDS
        #pragma unroll
        for (int mt = 0; mt < 4; ++mt) {
            #pragma unroll
            for (int rg = 0; rg < 4; ++rg) {
                float mx = fmaxf(fmaxf(s[mt][0][rg], s[mt][1][rg]),
                                 fmaxf(s[mt][2][rg], s[mt][3][rg]));
                #pragma unroll
                for (int msk = 1; msk < 16; msk <<= 1)
                    mx = fmaxf(mx, __shfl_xor(mx, msk));
                float p0 = __expf((s[mt][0][rg] - mx) * scale);
                float p1 = __expf((s[mt][1][rg] - mx) * scale);
                float p2 = __expf((s[mt][2][rg] - mx) * scale);
                float p3 = __expf((s[mt][3][rg] - mx) * scale);
                float sum = p0 + p1 + p2 + p3;
                #pragma unroll
                for (int msk = 1; msk < 16; msk <<= 1)
                    sum += __shfl_xor(sum, msk);
                float inv = 1.f / sum;
                int rowb = (mt * 16 + lq * 4 + rg) * 72 + lm;
                Pw[rowb + 0]  = f2b(p0 * inv);
                Pw[rowb + 16] = f2b(p1 * inv);
                Pw[rowb + 32] = f2b(p2 * inv);
                Pw[rowb + 48] = f2b(p3 * inv);
            }
        }
        __syncthreads();   // P visible (also orders vs other waves' stage use)
        // PV: O[64x32] = P[64x64] @ V_head[64x32]
        f32x4 o[4][2] = {{{0,0,0,0},{0,0,0,0}}, {{0,0,0,0},{0,0,0,0}},
                         {{0,0,0,0},{0,0,0,0}}, {{0,0,0,0},{0,0,0,0}}};
        #pragma unroll
        for (int kt = 0; kt < 2; ++kt) {
            short8 vb0 = *(const short8*)&VT[(g * 32 + 0  + lm) * 72 + kt * 32 + lq * 8];
            short8 vb1 = *(const short8*)&VT[(g * 32 + 16 + lm) * 72 + kt * 32 + lq * 8];
            #pragma unroll
            for (int mt = 0; mt < 4; ++mt) {
                short8 pa = *(const short8*)&Pw[(mt * 16 + lm) * 72 + kt * 32 + lq * 8];
                o[mt][0] = __builtin_amdgcn_mfma_f32_16x16x32_bf16(pa, vb0, o[mt][0], 0, 0, 0);
                o[mt][1] = __builtin_amdgcn_mfma_f32_16x16x32_bf16(pa, vb1, o[mt][1], 0, 0, 0);
            }
        }
        __syncthreads();   // reads done before next head overwrites Pw
        #pragma unroll
        for (int mt = 0; mt < 4; ++mt) {
            #pragma unroll
            for (int nt2 = 0; nt2 < 2; ++nt2) {
                #pragma unroll
                for (int rg = 0; rg < 4; ++rg) {
                    int row = mt * 16 + lq * 4 + rg;
                    int col = h * 32 + nt2 * 16 + lm;
                    Ob[(r0 + row) * 256 + col] = o[mt][nt2][rg];
                }
            }
        }
    }
}

// ------- O-projection GEMM (bf16x3) + gate + residual + transpose -------
__global__ __launch_bounds__(256) void oproj_gemm(
    const float* __restrict__ Ain, const float* __restrict__ Wo,
    const float* __restrict__ bo, const float* __restrict__ Xres,
    const float* __restrict__ gate, float* __restrict__ Out)
{
    __shared__ unsigned short Ah[64 * 128], Al[64 * 128];
    __shared__ unsigned short Bh[64 * 128], Bl[64 * 128];
    const int mt = blockIdx.x, nt = blockIdx.y, t = threadIdx.x;
    const int r0 = mt * 64, n0 = nt * 64;
    const int lm = t & 15, lq = (t & 63) >> 4, m16 = (t >> 6) * 16;
    f32x4 acc[4] = {{0,0,0,0},{0,0,0,0},{0,0,0,0},{0,0,0,0}};
    #pragma unroll 1
    for (int kh = 0; kh < 2; ++kh) {
        if (kh) __syncthreads();
        #pragma unroll
        for (int it = 0; it < 8; ++it) {
            int idx = it * 256 + t;
            int row = idx >> 5, seg = idx & 31;
            const float4 a4 = *(const float4*)(Ain + (r0 + row) * 256 + kh * 128 + seg * 4);
            ushort4 oh, ol;
            split2(a4.x, oh.x, ol.x); split2(a4.y, oh.y, ol.y);
            split2(a4.z, oh.z, ol.z); split2(a4.w, oh.w, ol.w);
            *(ushort4*)&Ah[sw128(row, seg * 4)] = oh;
            *(ushort4*)&Al[sw128(row, seg * 4)] = ol;
        }
        #pragma unroll
        for (int it = 0; it < 8; ++it) {
            int idx = it * 256 + t;
            int k = idx >> 4, sg = idx & 15;
            const float4 w4 = *(const float4*)(Wo + (kh * 128 + k) * 256 + n0 + sg * 4);
            unsigned short h, l;
            split2(w4.x, h, l); Bh[sw128(sg * 4 + 0, k)] = h; Bl[sw128(sg * 4 + 0, k)] = l;
            split2(w4.y, h, l); Bh[sw128(sg * 4 + 1, k)] = h; Bl[sw128(sg * 4 + 1, k)] = l;
            split2(w4.z, h, l); Bh[sw128(sg * 4 + 2, k)] = h; Bl[sw128(sg * 4 + 2, k)] = l;
            split2(w4.w, h, l); Bh[sw128(sg * 4 + 3, k)] = h; Bl[sw128(sg * 4 + 3, k)] = l;
        }
        __syncthreads();
        #pragma unroll
        for (int kk = 0; kk < 4; ++kk) {
            int k0 = kk * 32 + lq * 8;
            short8 ah = *(const short8*)&Ah[sw128(m16 + lm, k0)];
            short8 al = *(const short8*)&Al[sw128(m16 + lm, k0)];
            #pragma unroll
            for (int ct = 0; ct < 4; ++ct) {
                short8 bh = *(const short8*)&Bh[sw128(ct * 16 + lm, k0)];
                short8 bl = *(const short8*)&Bl[sw128(ct * 16 + lm, k0)];
                acc[ct] = __builtin_amdgcn_mfma_f32_16x16x32_bf16(ah, bh, acc[ct], 0, 0, 0);
                acc[ct] = __builtin_amdgcn_mfma_f32_16x16x32_bf16(al, bh, acc[ct], 0, 0, 0);
                acc[ct] = __builtin_amdgcn_mfma_f32_16x16x32_bf16(ah, bl, acc[ct], 0, 0, 0);
            }
        }
    }
    float sig = 1.f / (1.f + __expf(-gate[0]));
    #pragma unroll
    for (int ct = 0; ct < 4; ++ct) {
        #pragma unroll
        for (int rg = 0; rg < 4; ++rg) {
            int row = m16 + lq * 4 + rg;
            int col = n0 + ct * 16 + lm;
            int oidx = xrow_off(r0 + row) + col;
            Out[oidx] = Xres[oidx] + sig * (acc[ct][rg] + bo[col]);
        }
    }
}

extern "C" void kernel_launch(void* const* d_in, const int* in_sizes, int n_in,
                              void* d_out, int out_size, void* d_ws, size_t ws_size,
                              hipStream_t stream) {
    const float* x_spec = (const float*)d_in[0];
    const float* x_spat = (const float*)d_in[1];
    const float* ln_g[4] = {(const float*)d_in[2], (const float*)d_in[4],
                            (const float*)d_in[6], (const float*)d_in[8]};
    const float* ln_b[4] = {(const float*)d_in[3], (const float*)d_in[5],
                            (const float*)d_in[7], (const float*)d_in[9]};
    char* ws = (char*)d_ws;
    // workspace layout (~129 MiB total)
    float2* st_spec = (float2*)ws;                              // 512 KiB
    float2* st_spat = (float2*)(ws + ROWS * 8);                 // 512 KiB
    unsigned short* Qb = (unsigned short*)(ws + 2 * ROWS * 8);  // 32 MiB bf16
    unsigned short* Kb = Qb + (size_t)ROWS * 256;               // 16 MiB bf16
    unsigned short* Vb = Kb + (size_t)ROWS * 128;               // 16 MiB bf16
    float* Ab = (float*)(Vb + (size_t)ROWS * 128);              // 64 MiB fp32

    ln_stats<<<32768, 256, 0, stream>>>(x_spec, x_spat, st_spec, st_spat);

    for (int dir = 0; dir < 2; ++dir) {
        int base = 10 + dir * 8;
        const float* Wq = (const float*)d_in[base + 0];
        const float* bq = (const float*)d_in[base + 1];
        const float* Wk = (const float*)d_in[base + 2];
        const float* bk = (const float*)d_in[base + 3];
        const float* Wv = (const float*)d_in[base + 4];
        const float* bv = (const float*)d_in[base + 5];
        const float* Wo = (const float*)d_in[base + 6];
        const float* bo = (const float*)d_in[base + 7];
        const float* gate = (const float*)d_in[26 + dir];
        const float* xq   = dir == 0 ? x_spec : x_spat;
        const float* xkv  = dir == 0 ? x_spat : x_spec;
        const float2* stq  = dir == 0 ? st_spec : st_spat;
        const float2* stkv = dir == 0 ? st_spat : st_spec;
        const float* gq   = dir == 0 ? ln_g[0] : ln_g[2];
        const float* btq  = dir == 0 ? ln_b[0] : ln_b[2];
        const float* gkv  = dir == 0 ? ln_g[3] : ln_g[1];
        const float* btkv = dir == 0 ? ln_b[3] : ln_b[1];
        float* outp = (float*)d_out + (size_t)dir * NELT;

        qkv_gemm<<<dim3(1024, 8), 256, 0, stream>>>(
            xq, stq, gq, btq, xkv, stkv, gkv, btkv,
            Wq, Wk, Wv, bq, bk, bv, Qb, Kb, Vb);
        attn_kernel<<<1024, 256, 0, stream>>>(Qb, Kb, Vb, Ab);
        oproj_gemm<<<dim3(1024, 4), 256, 0, stream>>>(Ab, Wo, bo, xq, gate, outp);
    }
}

// Round 4
// 617.797 us; speedup vs baseline: 4.0227x; 1.5936x over previous
//
#include <hip/hip_runtime.h>

typedef short short8 __attribute__((ext_vector_type(8)));
typedef float f32x4 __attribute__((ext_vector_type(4)));

#define ROWS 65536     // B*C*S = 1024*64
#define NELT 16777216  // B*S*C*D per tensor

__device__ __forceinline__ float b2f(unsigned short u) {
    return __uint_as_float(((unsigned)u) << 16);
}
__device__ __forceinline__ unsigned short f2b(float f) {
    unsigned u = __float_as_uint(f);
    u += 0x7FFF + ((u >> 16) & 1);   // RTN-even
    return (unsigned short)(u >> 16);
}
// Markidis split: f ~= b2f(hi) + b2f(lo), residual ~2^-18 relative
__device__ __forceinline__ void split2(float f, unsigned short& hi, unsigned short& lo) {
    unsigned short h = f2b(f);
    hi = h;
    lo = f2b(f - b2f(h));
}
// row r of the (BC*S, D) flattened view -> flat offset into x (B,S,C,D)
__device__ __forceinline__ int xrow_off(int r) {
    int n = r >> 6, s = r & 63;      // n = b*128+c, s = token
    int b = n >> 7, c = n & 127;
    return (((b << 6) + s) * 128 + c) << 8;  // ((b*64+s)*128+c)*256
}
// XOR-swizzled LDS element offset, 64x256 bf16 tile, 8-elem chunks.
// (row&7) < 8 so the XOR only permutes the low-3 chunk bits.
__device__ __forceinline__ int sw256(int row, int k) {
    return row * 256 + ((((k >> 3) ^ (row & 7)) << 3) | (k & 7));
}
// linearized B-fragment offset (in shorts): [nt][kk][ct][lq][lm][hi8|lo8]
__device__ __forceinline__ int boff(int nt, int kk, int ct, int lq, int lm) {
    return ((((nt * 8 + kk) * 4 + ct) * 4 + lq) * 16 + lm) * 16;
}

// ---- weight pre-linearization into MFMA B-fragment order (per dir) ----
// 16384 threads: lm=tid&15, lq=(tid>>4)&3, ct=(tid>>6)&3, kk=(tid>>8)&7, nt=tid>>11
// QKV: nt 0..3 -> Wq cols, 4..5 -> Wk, 6..7 -> Wv.  O: nt 0..3 -> Wo cols.
__global__ __launch_bounds__(256) void w_prep(
    const float* __restrict__ Wq, const float* __restrict__ Wk,
    const float* __restrict__ Wv, const float* __restrict__ Wo,
    unsigned short* __restrict__ Bqkv, unsigned short* __restrict__ Bo)
{
    const int tid = blockIdx.x * 256 + threadIdx.x;
    const int lm = tid & 15, lq = (tid >> 4) & 3, ct = (tid >> 6) & 3;
    const int kk = (tid >> 8) & 7, nt = tid >> 11;
    const int c = ct * 16 + lm;
    {
        const float* W; int ldw, col;
        if (nt < 4)      { W = Wq; ldw = 256; col = nt * 64 + c; }
        else if (nt < 6) { W = Wk; ldw = 128; col = (nt - 4) * 64 + c; }
        else             { W = Wv; ldw = 128; col = (nt - 6) * 64 + c; }
        short8 h8, l8;
        #pragma unroll
        for (int j = 0; j < 8; ++j) {
            int k = kk * 32 + lq * 8 + j;
            unsigned short h, l;
            split2(W[k * ldw + col], h, l);
            h8[j] = (short)h; l8[j] = (short)l;
        }
        int off = boff(nt, kk, ct, lq, lm);
        *(short8*)&Bqkv[off] = h8;
        *(short8*)&Bqkv[off + 8] = l8;
    }
    if (nt < 4) {
        int col = nt * 64 + c;
        short8 h8, l8;
        #pragma unroll
        for (int j = 0; j < 8; ++j) {
            int k = kk * 32 + lq * 8 + j;
            unsigned short h, l;
            split2(Wo[k * 256 + col], h, l);
            h8[j] = (short)h; l8[j] = (short)l;
        }
        int off = boff(nt, kk, ct, lq, lm);
        *(short8*)&Bo[off] = h8;
        *(short8*)&Bo[off + 8] = l8;
    }
}

// ---- fused LN(stats+apply) + QKV projection GEMM (bf16x3) ----
// grid (1024, 2): y=0 -> Q (xq, 256 cols), y=1 -> K|V (xkv, 128+128 cols).
// Waves partition columns (wave w -> cols w*64..w*64+63); A staged once.
__global__ __launch_bounds__(256) void qkv_gemm(
    const float* __restrict__ xq, const float* __restrict__ gq, const float* __restrict__ btq,
    const float* __restrict__ xkv, const float* __restrict__ gkv, const float* __restrict__ btkv,
    const unsigned short* __restrict__ Blin,
    const float* __restrict__ bq, const float* __restrict__ bk, const float* __restrict__ bv,
    unsigned short* __restrict__ Qb, unsigned short* __restrict__ Kb,
    unsigned short* __restrict__ Vb)
{
    __shared__ unsigned short Ah[64 * 256], Al[64 * 256];   // 64 KB
    const int mt = blockIdx.x, y = blockIdx.y, t = threadIdx.x;
    const float* X  = y ? xkv  : xq;
    const float* G  = y ? gkv  : gq;
    const float* BT = y ? btkv : btq;
    const int r0 = mt * 64;
    const int w = t >> 6, l = t & 63;
    // stage A: each wave-iteration covers exactly one full row (64 lanes x float4)
    const float4 gv = *(const float4*)(G + l * 4);
    const float4 b4 = *(const float4*)(BT + l * 4);
    #pragma unroll
    for (int it = 0; it < 16; ++it) {
        int row = it * 4 + w;
        const float4 xv = *(const float4*)(X + xrow_off(r0 + row) + l * 4);
        float s1 = xv.x + xv.y + xv.z + xv.w;
        float s2 = xv.x * xv.x + xv.y * xv.y + xv.z * xv.z + xv.w * xv.w;
        #pragma unroll
        for (int m = 1; m < 64; m <<= 1) {
            s1 += __shfl_xor(s1, m);
            s2 += __shfl_xor(s2, m);
        }
        float mu = s1 * (1.f / 256.f);
        float rstd = rsqrtf(s2 * (1.f / 256.f) - mu * mu + 1e-5f);
        float v0 = (xv.x - mu) * rstd * gv.x + b4.x;
        float v1 = (xv.y - mu) * rstd * gv.y + b4.y;
        float v2 = (xv.z - mu) * rstd * gv.z + b4.z;
        float v3 = (xv.w - mu) * rstd * gv.w + b4.w;
        ushort4 oh, ol;
        split2(v0, oh.x, ol.x); split2(v1, oh.y, ol.y);
        split2(v2, oh.z, ol.z); split2(v3, oh.w, ol.w);
        *(ushort4*)&Ah[sw256(row, l * 4)] = oh;
        *(ushort4*)&Al[sw256(row, l * 4)] = ol;
    }
    __syncthreads();
    const int lm = l & 15, lq = l >> 4;
    const int ntw = y * 4 + w;
    f32x4 acc[4][4] = {};
    #pragma unroll
    for (int kk = 0; kk < 8; ++kk) {
        int k0 = kk * 32 + lq * 8;
        short8 ah[4], al[4];
        #pragma unroll
        for (int m = 0; m < 4; ++m) {
            ah[m] = *(const short8*)&Ah[sw256(m * 16 + lm, k0)];
            al[m] = *(const short8*)&Al[sw256(m * 16 + lm, k0)];
        }
        #pragma unroll
        for (int i = 0; i < 4; ++i) {
            int off = boff(ntw, kk, i, lq, lm);
            short8 bh = *(const short8*)&Blin[off];
            short8 bl = *(const short8*)&Blin[off + 8];
            #pragma unroll
            for (int m = 0; m < 4; ++m) {
                acc[m][i] = __builtin_amdgcn_mfma_f32_16x16x32_bf16(ah[m], bh, acc[m][i], 0, 0, 0);
                acc[m][i] = __builtin_amdgcn_mfma_f32_16x16x32_bf16(al[m], bh, acc[m][i], 0, 0, 0);
                acc[m][i] = __builtin_amdgcn_mfma_f32_16x16x32_bf16(ah[m], bl, acc[m][i], 0, 0, 0);
            }
        }
    }
    #pragma unroll
    for (int i = 0; i < 4; ++i) {
        int cblk = w * 64 + i * 16 + lm;     // col within this block's 256-col slab
        float bias; unsigned short* outp; int ldo, ocol;
        if (y == 0)          { bias = bq[cblk];       outp = Qb; ldo = 256; ocol = cblk; }
        else if (cblk < 128) { bias = bk[cblk];       outp = Kb; ldo = 128; ocol = cblk; }
        else                 { bias = bv[cblk - 128]; outp = Vb; ldo = 128; ocol = cblk - 128; }
        #pragma unroll
        for (int m = 0; m < 4; ++m) {
            #pragma unroll
            for (int rg = 0; rg < 4; ++rg) {
                int row = m * 16 + lq * 4 + rg;
                outp[(r0 + row) * ldo + ocol] = f2b(acc[m][i][rg] + bias);
            }
        }
    }
}

// ---------------- MFMA attention: one block per sequence ----------------
__global__ __launch_bounds__(256) void attn_kernel(
    const unsigned short* __restrict__ Qb, const unsigned short* __restrict__ Kb,
    const unsigned short* __restrict__ Vb, float* __restrict__ Ob)
{
    __shared__ unsigned short VT[128 * 72];      // V^T: [dim][key], stride 72
    __shared__ unsigned short Pl[4 * 64 * 72];   // per-wave P, stride 72
    const int n = blockIdx.x, t = threadIdx.x;
    const int r0 = n * 64;
    #pragma unroll
    for (int it = 0; it < 8; ++it) {
        int idx = it * 256 + t;
        int row = idx >> 5, seg = idx & 31;
        ushort4 v4 = *(const ushort4*)&Vb[(r0 + row) * 128 + seg * 4];
        VT[(seg * 4 + 0) * 72 + row] = v4.x;
        VT[(seg * 4 + 1) * 72 + row] = v4.y;
        VT[(seg * 4 + 2) * 72 + row] = v4.z;
        VT[(seg * 4 + 3) * 72 + row] = v4.w;
    }
    __syncthreads();
    const int wave = t >> 6, l = t & 63, lm = l & 15, lq = l >> 4;
    const int g = wave;
    unsigned short* Pw = &Pl[wave * 64 * 72];
    const float scale = 0.17677669529663687f;    // 1/sqrt(32)
    short8 kf[4];
    #pragma unroll
    for (int nt = 0; nt < 4; ++nt)
        kf[nt] = *(const short8*)&Kb[(r0 + nt * 16 + lm) * 128 + g * 32 + lq * 8];
    #pragma unroll 1
    for (int hi = 0; hi < 2; ++hi) {
        const int h = g * 2 + hi;
        f32x4 s[4][4];
        #pragma unroll
        for (int mt = 0; mt < 4; ++mt) {
            short8 qf = *(const short8*)&Qb[(r0 + mt * 16 + lm) * 256 + h * 32 + lq * 8];
            #pragma unroll
            for (int nt = 0; nt < 4; ++nt) {
                f32x4 z = {0, 0, 0, 0};
                s[mt][nt] = __builtin_amdgcn_mfma_f32_16x16x32_bf16(qf, kf[nt], z, 0, 0, 0);
            }
        }
        #pragma unroll
        for (int mt = 0; mt < 4; ++mt) {
            #pragma unroll
            for (int rg = 0; rg < 4; ++rg) {
                float mx = fmaxf(fmaxf(s[mt][0][rg], s[mt][1][rg]),
                                 fmaxf(s[mt][2][rg], s[mt][3][rg]));
                #pragma unroll
                for (int msk = 1; msk < 16; msk <<= 1)
                    mx = fmaxf(mx, __shfl_xor(mx, msk));
                float p0 = __expf((s[mt][0][rg] - mx) * scale);
                float p1 = __expf((s[mt][1][rg] - mx) * scale);
                float p2 = __expf((s[mt][2][rg] - mx) * scale);
                float p3 = __expf((s[mt][3][rg] - mx) * scale);
                float sum = p0 + p1 + p2 + p3;
                #pragma unroll
                for (int msk = 1; msk < 16; msk <<= 1)
                    sum += __shfl_xor(sum, msk);
                float inv = 1.f / sum;
                int rowb = (mt * 16 + lq * 4 + rg) * 72 + lm;
                Pw[rowb + 0]  = f2b(p0 * inv);
                Pw[rowb + 16] = f2b(p1 * inv);
                Pw[rowb + 32] = f2b(p2 * inv);
                Pw[rowb + 48] = f2b(p3 * inv);
            }
        }
        __syncthreads();
        f32x4 o[4][2] = {{{0,0,0,0},{0,0,0,0}}, {{0,0,0,0},{0,0,0,0}},
                         {{0,0,0,0},{0,0,0,0}}, {{0,0,0,0},{0,0,0,0}}};
        #pragma unroll
        for (int kt = 0; kt < 2; ++kt) {
            short8 vb0 = *(const short8*)&VT[(g * 32 + 0  + lm) * 72 + kt * 32 + lq * 8];
            short8 vb1 = *(const short8*)&VT[(g * 32 + 16 + lm) * 72 + kt * 32 + lq * 8];
            #pragma unroll
            for (int mt = 0; mt < 4; ++mt) {
                short8 pa = *(const short8*)&Pw[(mt * 16 + lm) * 72 + kt * 32 + lq * 8];
                o[mt][0] = __builtin_amdgcn_mfma_f32_16x16x32_bf16(pa, vb0, o[mt][0], 0, 0, 0);
                o[mt][1] = __builtin_amdgcn_mfma_f32_16x16x32_bf16(pa, vb1, o[mt][1], 0, 0, 0);
            }
        }
        __syncthreads();
        #pragma unroll
        for (int mt = 0; mt < 4; ++mt) {
            #pragma unroll
            for (int nt2 = 0; nt2 < 2; ++nt2) {
                #pragma unroll
                for (int rg = 0; rg < 4; ++rg) {
                    int row = mt * 16 + lq * 4 + rg;
                    int col = h * 32 + nt2 * 16 + lm;
                    Ob[(r0 + row) * 256 + col] = o[mt][nt2][rg];
                }
            }
        }
    }
}

// ------- O-projection GEMM (bf16x3) + gate + residual + transpose -------
// grid (1024): waves partition columns; A (fp32 attn out) staged once.
__global__ __launch_bounds__(256) void oproj_gemm(
    const float* __restrict__ Ain, const unsigned short* __restrict__ Bo,
    const float* __restrict__ bo, const float* __restrict__ Xres,
    const float* __restrict__ gate, float* __restrict__ Out)
{
    __shared__ unsigned short Ah[64 * 256], Al[64 * 256];   // 64 KB
    const int mt = blockIdx.x, t = threadIdx.x;
    const int r0 = mt * 64;
    const int w = t >> 6, l = t & 63;
    #pragma unroll
    for (int it = 0; it < 16; ++it) {
        int row = it * 4 + w;
        const float4 a4 = *(const float4*)(Ain + (r0 + row) * 256 + l * 4);
        ushort4 oh, ol;
        split2(a4.x, oh.x, ol.x); split2(a4.y, oh.y, ol.y);
        split2(a4.z, oh.z, ol.z); split2(a4.w, oh.w, ol.w);
        *(ushort4*)&Ah[sw256(row, l * 4)] = oh;
        *(ushort4*)&Al[sw256(row, l * 4)] = ol;
    }
    __syncthreads();
    const int lm = l & 15, lq = l >> 4;
    f32x4 acc[4][4] = {};
    #pragma unroll
    for (int kk = 0; kk < 8; ++kk) {
        int k0 = kk * 32 + lq * 8;
        short8 ah[4], al[4];
        #pragma unroll
        for (int m = 0; m < 4; ++m) {
            ah[m] = *(const short8*)&Ah[sw256(m * 16 + lm, k0)];
            al[m] = *(const short8*)&Al[sw256(m * 16 + lm, k0)];
        }
        #pragma unroll
        for (int i = 0; i < 4; ++i) {
            int off = boff(w, kk, i, lq, lm);
            short8 bh = *(const short8*)&Bo[off];
            short8 bl = *(const short8*)&Bo[off + 8];
            #pragma unroll
            for (int m = 0; m < 4; ++m) {
                acc[m][i] = __builtin_amdgcn_mfma_f32_16x16x32_bf16(ah[m], bh, acc[m][i], 0, 0, 0);
                acc[m][i] = __builtin_amdgcn_mfma_f32_16x16x32_bf16(al[m], bh, acc[m][i], 0, 0, 0);
                acc[m][i] = __builtin_amdgcn_mfma_f32_16x16x32_bf16(ah[m], bl, acc[m][i], 0, 0, 0);
            }
        }
    }
    float sig = 1.f / (1.f + __expf(-gate[0]));
    #pragma unroll
    for (int i = 0; i < 4; ++i) {
        int col = w * 64 + i * 16 + lm;
        float bias = bo[col];
        #pragma unroll
        for (int m = 0; m < 4; ++m) {
            #pragma unroll
            for (int rg = 0; rg < 4; ++rg) {
                int row = m * 16 + lq * 4 + rg;
                int oidx = xrow_off(r0 + row) + col;
                Out[oidx] = Xres[oidx] + sig * (acc[m][i][rg] + bias);
            }
        }
    }
}

extern "C" void kernel_launch(void* const* d_in, const int* in_sizes, int n_in,
                              void* d_out, int out_size, void* d_ws, size_t ws_size,
                              hipStream_t stream) {
    const float* x_spec = (const float*)d_in[0];
    const float* x_spat = (const float*)d_in[1];
    const float* ln_g[4] = {(const float*)d_in[2], (const float*)d_in[4],
                            (const float*)d_in[6], (const float*)d_in[8]};
    const float* ln_b[4] = {(const float*)d_in[3], (const float*)d_in[5],
                            (const float*)d_in[7], (const float*)d_in[9]};
    char* ws = (char*)d_ws;
    // workspace layout (~129.5 MiB)
    unsigned short* Bqkv[2] = {(unsigned short*)ws,
                               (unsigned short*)(ws + (512 << 10))};     // 2 x 512 KiB
    unsigned short* BoL[2]  = {(unsigned short*)(ws + (1024 << 10)),
                               (unsigned short*)(ws + (1280 << 10))};    // 2 x 256 KiB
    char* big = ws + (1536 << 10);
    unsigned short* Qb = (unsigned short*)big;                  // 32 MiB bf16
    unsigned short* Kb = Qb + (size_t)ROWS * 256;               // 16 MiB bf16
    unsigned short* Vb = Kb + (size_t)ROWS * 128;               // 16 MiB bf16
    float* Ab = (float*)(Vb + (size_t)ROWS * 128);              // 64 MiB fp32

    for (int dir = 0; dir < 2; ++dir) {
        int base = 10 + dir * 8;
        w_prep<<<64, 256, 0, stream>>>(
            (const float*)d_in[base + 0], (const float*)d_in[base + 2],
            (const float*)d_in[base + 4], (const float*)d_in[base + 6],
            Bqkv[dir], BoL[dir]);
    }
    for (int dir = 0; dir < 2; ++dir) {
        int base = 10 + dir * 8;
        const float* bq = (const float*)d_in[base + 1];
        const float* bk = (const float*)d_in[base + 3];
        const float* bv = (const float*)d_in[base + 5];
        const float* bo = (const float*)d_in[base + 7];
        const float* gate = (const float*)d_in[26 + dir];
        const float* xq   = dir == 0 ? x_spec : x_spat;
        const float* xkv  = dir == 0 ? x_spat : x_spec;
        const float* gq   = dir == 0 ? ln_g[0] : ln_g[2];
        const float* btq  = dir == 0 ? ln_b[0] : ln_b[2];
        const float* gkv  = dir == 0 ? ln_g[3] : ln_g[1];
        const float* btkv = dir == 0 ? ln_b[3] : ln_b[1];
        float* outp = (float*)d_out + (size_t)dir * NELT;

        qkv_gemm<<<dim3(1024, 2), 256, 0, stream>>>(
            xq, gq, btq, xkv, gkv, btkv, Bqkv[dir],
            bq, bk, bv, Qb, Kb, Vb);
        attn_kernel<<<1024, 256, 0, stream>>>(Qb, Kb, Vb, Ab);
        oproj_gemm<<<1024, 256, 0, stream>>>(Ab, BoL[dir], bo, xq, gate, outp);
    }
}